// Round 4
// baseline (208.210 us; speedup 1.0000x reference)
//
#include <hip/hip_runtime.h>
#include <math.h>

#define DNUM 1024
#define CNUM 32000
#define NT 1024            // 16 waves/block
#define R 2                // rows per block (amortize e1/e3 loads across 2 rows)
#define GRID (DNUM / R)    // 512 blocks -> 2 resident blocks/CU x 16 waves = 32 waves/CU
#define KC 8               // coarse bins (0.675 sigma each), span [-0.5s, +4.9s]
#define KF 4               // fine bins (0.169 sigma) -> same final resolution as KC4/KF8
#define NQ (CNUM / 4)      // 8000 4-class chunks
#define NFULL (NQ / NT)    // 7 full iterations
#define TAILN (NQ - NFULL*NT) // 832 = 13 waves exactly (wave-aligned tail)

#define L2E 1.4426950408889634f
#define LN2 0.6931471805599453f

typedef float v2f __attribute__((ext_vector_type(2)));

__device__ __forceinline__ v2f splat2(float s) { v2f v; v.x = s; v.y = s; return v; }

__device__ __forceinline__ float wave_red_sum(float v) {
    #pragma unroll
    for (int o = 32; o > 0; o >>= 1) v += __shfl_down(v, o, 64);
    return v;
}

// One block = 2 rows, NT=1024 (16 waves), two streaming passes over L2-resident
// e1/e3. Config rationale (rounds 0-3):
//  - R=2 halves global-load instrs+latency events per row-eval (r0: 54us beat
//    r2's R=1 57us despite half the occupancy).
//  - Occupancy was GRID-capped, not LDS-capped: (DNUM/R) blocks x NT threads
//    must give 32 waves/CU -> NT=1024 with R=2 (2 blocks/CU x 16 waves).
//  - Per-thread-private slot arrays scale with NT, so histogram levels move to
//    KC=8 coarse / KF=4 fine: SAME 0.169-sigma final resolution, pool = 64 KB
//    (fits 80 KB/block at 2 blocks/CU). Pass-1 RMW chains deepen to 4-step per
//    row; the doubled TLP (32 waves/CU) hides that latency.
//  - NO prefetch, NO moment accumulators (round 3: both together -> scratch
//    spills, WRITE_SIZE 15MB, +12us). Plain += on LDS (round 1: unsafeAtomicAdd
//    on LDS lowers to FLAT atomics, 5x regression).
__global__ __launch_bounds__(NT, 8) void akl_rows(
    const float* __restrict__ h1, const float* __restrict__ e1,
    const float* __restrict__ h3, const float* __restrict__ e3,
    float* __restrict__ out)
{
    const int tid  = threadIdx.x;
    const int lane = tid & 63, wid = tid >> 6;   // 16 waves
    const int row0 = blockIdx.x * R;

    __shared__ float pool[16384];  // 64 KB
    // P1: row r region at r*8192, slot = bin*NT + tid (KC=8 bins)
    // P2: fine e2 row r at r*4096; fine gap row r at 8192 + r*4096 (KF=4)
    __shared__ float red[96];      // 16 waves x 6 (pass1) / x4 (pass2)
    __shared__ float shCS[R*KC];
    __shared__ float shFP[R*KF], shFG[R*KF];
    __shared__ float shA[R][7];    // c, thr, fkl, rkl, icwF, c0Fs, Spre

    // Per-row coefficients, log2 domain
    float a1L[R], b1L[R], a2L[R], b2L[R], mh1L[R], mh2L[R], icwC[R], c0C[R];
    #pragma unroll
    for (int r = 0; r < R; r++) {
        a1L[r] = h1[2*(row0+r)] * L2E; b1L[r] = h1[2*(row0+r)+1] * L2E;
        a2L[r] = h3[2*(row0+r)] * L2E; b2L[r] = h3[2*(row0+r)+1] * L2E;
        mh1L[r] = 6.0f * (fabsf(a1L[r]) + fabsf(b1L[r]));   // safe shift
        mh2L[r] = 6.0f * (fabsf(a2L[r]) + fabsf(b2L[r]));
        float sp = fmaxf(sqrtf(a2L[r]*a2L[r] + b2L[r]*b2L[r]), 1e-6f);
        icwC[r] = 1.0f / (0.675f * sp);          // 8 cells over [-0.5s, +4.9s]
        c0C[r] = 0.5f/0.675f + mh2L[r]*icwC[r];  // cb=(int)(l2s*icwC + c0C)
    }
    for (int i = tid; i < 16384; i += NT) pool[i] = 0.f;
    __syncthreads();                                                   // B0

    const float4* __restrict__ E1 = (const float4*)e1;
    const float4* __restrict__ E3 = (const float4*)e3;

    // tail: TAILN=832 -> waves 0..12 take one extra chunk, no intra-wave split
    const int cnt = NFULL + ((tid < TAILN) ? 1 : 0);

    // ================= Pass 1: moments + coarse 8-bin partition =============
    v2f U1v[R], S1v[R], S2v[R];
    #pragma unroll
    for (int r = 0; r < R; r++) { U1v[r] = splat2(0.f); S1v[r] = splat2(0.f); S2v[r] = splat2(0.f); }

    #pragma unroll 1
    for (int it = 0; it < cnt; ++it) {
        const int j = it*NT + tid;
        float4 A0 = E1[2*j], A1 = E1[2*j+1];
        float4 B0 = E3[2*j], B1 = E3[2*j+1];
        #pragma unroll
        for (int r = 0; r < R; r++) {
            const v2f a1v = splat2(a1L[r]), b1v = splat2(b1L[r]);
            const v2f a2v = splat2(a2L[r]), b2v = splat2(b2L[r]);
            const v2f m1v = splat2(-mh1L[r]), m2v = splat2(-mh2L[r]);
            const v2f icv = splat2(icwC[r]), c0v = splat2(c0C[r]);
            float* H = pool + r*8192;
            #pragma unroll
            for (int p = 0; p < 2; p++) {
                float4 A = p ? A1 : A0, B = p ? B1 : B0;
                v2f X1; X1.x = A.x; X1.y = A.z;
                v2f Y1; Y1.x = A.y; Y1.y = A.w;
                v2f X3; X3.x = B.x; X3.y = B.z;
                v2f Y3; Y3.x = B.y; Y3.y = B.w;
                v2f l1 = a1v*X1 + (b1v*Y1 + m1v);     // pk_fma
                v2f l2 = a2v*X3 + (b2v*Y3 + m2v);
                v2f e1v; e1v.x = __builtin_amdgcn_exp2f(l1.x);
                         e1v.y = __builtin_amdgcn_exp2f(l1.y);
                v2f e2v; e2v.x = __builtin_amdgcn_exp2f(l2.x);
                         e2v.y = __builtin_amdgcn_exp2f(l2.y);
                v2f dp = l2 - l1;                     // corrected post-pass
                U1v[r] += e1v;
                S1v[r] += e1v * dp;
                S2v[r] += e2v * dp;
                v2f t = l2*icv + c0v;
                float t0 = fminf(fmaxf(t.x, 0.f), 7.f);   // med3
                float t1 = fminf(fmaxf(t.y, 0.f), 7.f);
                int b0 = (int)t0, b1i = (int)t1;
                // per-thread-private slots; 4-step chain per row, TLP-hidden
                H[b0*NT + tid]  += e2v.x;
                H[b1i*NT + tid] += e2v.y;
            }
        }
    }

    #pragma unroll
    for (int r = 0; r < R; r++) {
        float u = wave_red_sum(U1v[r].x + U1v[r].y);
        float s1 = wave_red_sum(S1v[r].x + S1v[r].y);
        float s2 = wave_red_sum(S2v[r].x + S2v[r].y);
        if (lane == 0) {
            red[wid*6 + r*3 + 0] = u;
            red[wid*6 + r*3 + 1] = s1;
            red[wid*6 + r*3 + 2] = s2;
        }
    }
    __syncthreads();                                                   // B1

    // ---- Reduce coarse histogram: 16 groups (r x bin) x 64 lanes ----
    {
        int r = wid >> 3, b = wid & 7;           // group = wave
        const float* H = pool + r*8192 + b*NT;
        float s = 0.f;
        #pragma unroll
        for (int t = 0; t < NT/64; t++) s += H[lane + t*64];
        s = wave_red_sum(s);
        if (lane == 0) shCS[r*KC + b] = s;
    }
    __syncthreads();                                                   // B2

    // ---- Row params + coarse crossing cell (one thread per row) ----
    if (tid < R) {
        const int r = tid;
        float U1s = 0, S1s = 0, S2s = 0;
        for (int w = 0; w < 16; w++) {
            U1s += red[w*6 + r*3 + 0];
            S1s += red[w*6 + r*3 + 1];
            S2s += red[w*6 + r*3 + 2];
        }
        float U2s = 0.f;
        #pragma unroll
        for (int i = 0; i < KC; i++) U2s += shCS[r*KC + i];
        float mh1r = r ? mh1L[1] : mh1L[0];
        float mh2r = r ? mh2L[1] : mh2L[0];
        float a2r = r ? a2L[1] : a2L[0];
        float b2r = r ? b2L[1] : b2L[0];
        float dmh = mh2r - mh1r;
        S1s += dmh * U1s;                        // exact shift correction
        S2s += dmh * U2s;
        float M1 = mh1r + __builtin_amdgcn_logf(U1s);
        float M2 = mh2r + __builtin_amdgcn_logf(U2s);
        float delta = M2 - M1;
        float thr = 0.5f * U2s;
        float S = 0.f; int bsel = KC-1;
        for (int i = 0; i < KC; i++) {
            float m = shCS[r*KC + i];
            if (S + m >= thr) { bsel = i; break; }
            S += m;
        }
        float sp = fmaxf(sqrtf(a2r*a2r + b2r*b2r), 1e-6f);
        float wc  = 0.675f * sp;                 // coarse cell width
        float loS_s = fmaf((float)bsel, wc, -0.5f*sp) - mh2r;  // shifted space
        float icwF = (float)KF / wc;
        shA[r][0] = U2s / U1s;                   // c (gap scale fold)
        shA[r][1] = thr;
        shA[r][2] = LN2 * (S2s/U2s - delta);     // fkl
        shA[r][3] = LN2 * (delta - S1s/U1s);     // rkl
        shA[r][4] = icwF;
        shA[r][5] = -loS_s * icwF;               // c0Fs: t=l2s*icwF+c0Fs
        shA[r][6] = S;                           // Spre (unnorm prefix below cell)
    }
    // re-zero pool for fine pass
    for (int i = tid; i < 16384; i += NT) pool[i] = 0.f;
    __syncthreads();                                                   // B3

    // ================= Pass 2: gap stats + fine partition ===================
    float cR[R], icwFl[R], c0Fl[R];
    #pragma unroll
    for (int r = 0; r < R; r++) {
        cR[r] = shA[r][0]; icwFl[r] = shA[r][4]; c0Fl[r] = shA[r][5];
    }
    v2f gtv[R], Gpv[R];
    #pragma unroll
    for (int r = 0; r < R; r++) { gtv[r] = splat2(0.f); Gpv[r] = splat2(0.f); }

    #pragma unroll 1
    for (int it = 0; it < cnt; ++it) {
        const int j = it*NT + tid;
        float4 A0 = E1[2*j], A1 = E1[2*j+1];
        float4 B0 = E3[2*j], B1 = E3[2*j+1];
        #pragma unroll
        for (int r = 0; r < R; r++) {
            const v2f a1v = splat2(a1L[r]), b1v = splat2(b1L[r]);
            const v2f a2v = splat2(a2L[r]), b2v = splat2(b2L[r]);
            const v2f m1v = splat2(-mh1L[r]), m2v = splat2(-mh2L[r]);
            const v2f cv = splat2(-cR[r]);
            const v2f icv = splat2(icwFl[r]), c0v = splat2(c0Fl[r]);
            float* HP = pool + r*4096;
            float* HG = pool + 8192 + r*4096;
            #pragma unroll
            for (int p = 0; p < 2; p++) {
                float4 A = p ? A1 : A0, B = p ? B1 : B0;
                v2f X1; X1.x = A.x; X1.y = A.z;
                v2f Y1; Y1.x = A.y; Y1.y = A.w;
                v2f X3; X3.x = B.x; X3.y = B.z;
                v2f Y3; Y3.x = B.y; Y3.y = B.w;
                v2f l1 = a1v*X1 + (b1v*Y1 + m1v);
                v2f l2 = a2v*X3 + (b2v*Y3 + m2v);
                v2f e1v; e1v.x = __builtin_amdgcn_exp2f(l1.x);
                         e1v.y = __builtin_amdgcn_exp2f(l1.y);
                v2f e2v; e2v.x = __builtin_amdgcn_exp2f(l2.x);
                         e2v.y = __builtin_amdgcn_exp2f(l2.y);
                v2f d = cv*e1v + e2v;                // e2 - c*e1 (pk_fma)
                v2f gap; gap.x = fabsf(d.x); gap.y = fabsf(d.y);
                gtv[r] += gap;
                v2f t = l2*icv + c0v;
                Gpv[r].x += (t.x < 0.f) ? gap.x : 0.f;
                Gpv[r].y += (t.y < 0.f) ? gap.y : 0.f;
                if (t.x >= 0.f && t.x < (float)KF) {   // rare (~0.5%)
                    int fb = (int)t.x;
                    HP[fb*NT + tid] += e2v.x;
                    HG[fb*NT + tid] += gap.x;
                }
                if (t.y >= 0.f && t.y < (float)KF) {
                    int fb = (int)t.y;
                    HP[fb*NT + tid] += e2v.y;
                    HG[fb*NT + tid] += gap.y;
                }
            }
        }
    }

    #pragma unroll
    for (int r = 0; r < R; r++) {
        float a = wave_red_sum(gtv[r].x + gtv[r].y);
        float b = wave_red_sum(Gpv[r].x + Gpv[r].y);
        if (lane == 0) { red[wid*4 + r*2 + 0] = a; red[wid*4 + r*2 + 1] = b; }
    }
    __syncthreads();                                                   // B4

    // ---- Reduce fine histograms: 16 groups (isG x r x fb) x 64 lanes ----
    {
        int isG = wid >> 3;                      // 0: P, 1: G
        int rem = wid & 7;
        int r = rem >> 2, b = rem & 3;
        const float* H = pool + isG*8192 + r*4096 + b*NT;
        float s = 0.f;
        #pragma unroll
        for (int t = 0; t < NT/64; t++) s += H[lane + t*64];
        s = wave_red_sum(s);
        if (lane == 0) {
            if (isG) shFG[r*KF + b] = s; else shFP[r*KF + b] = s;
        }
    }
    __syncthreads();                                                   // B5

    // ---- Walk fine bins, secant-interpolate 0.5 crossing, output ----
    if (tid < R) {
        const int r = tid;
        float gts = 0, Gp = 0;
        for (int w = 0; w < 16; w++) {
            gts += red[w*4 + r*2 + 0];
            Gp  += red[w*4 + r*2 + 1];
        }
        float thr = shA[r][1], fkl = shA[r][2], rkl = shA[r][3];
        float S = shA[r][6], G = Gp;
        bool done = false;
        #pragma unroll
        for (int i = 0; i < KF; i++) {
            if (!done) {
                float p = shFP[r*KF + i], g = shFG[r*KF + i];
                float ns = S + p;
                if (ns >= thr) {
                    float f = (thr - S) / fmaxf(p, 1e-30f);
                    f = fminf(fmaxf(f, 0.f), 1.f);
                    G += f * g;
                    done = true;
                } else { S = ns; G += g; }
            }
        }
        float gl = G;                    // g_tail (unnormalized: scale cancels)
        float gh = gts - gl;             // g_head
        float akl = (gh*fkl + gl*rkl) / gts;
        unsafeAtomicAdd(out, akl * (1.0f/(float)DNUM));
    }
}

extern "C" void kernel_launch(void* const* d_in, const int* in_sizes, int n_in,
                              void* d_out, int out_size, void* d_ws, size_t ws_size,
                              hipStream_t stream) {
    const float* h1 = (const float*)d_in[0];
    const float* e1 = (const float*)d_in[1];
    const float* h3 = (const float*)d_in[2];
    const float* e3 = (const float*)d_in[3];
    hipMemsetAsync(d_out, 0, sizeof(float), stream);   // capture-safe
    akl_rows<<<GRID, NT, 0, stream>>>(h1, e1, h3, e3, (float*)d_out);
}

// Round 5
// 106.157 us; speedup vs baseline: 1.9613x; 1.9613x over previous
//
#include <hip/hip_runtime.h>
#include <math.h>

#define DNUM 1024
#define CNUM 32000
#define NT 512             // 8 waves/block
#define R 2                // rows per block
#define GRID (DNUM / R)    // 512 blocks -> 2 resident blocks/CU
#define KC 4               // coarse bins (1.35 sigma each), span [-0.5s, +4.9s]
#define KF 8               // fine bins   (0.169 sigma each)
#define NQ (CNUM / 4)      // 8000 4-class chunks
#define NFULL (NQ / NT)    // 15 full iterations
#define TAILN (NQ - NFULL*NT) // 320

#define L2E 1.4426950408889634f
#define LN2 0.6931471805599453f

typedef float v2f __attribute__((ext_vector_type(2)));

__device__ __forceinline__ v2f splat2(float s) { v2f v; v.x = s; v.y = s; return v; }

__device__ __forceinline__ float wave_red_sum(float v) {
    #pragma unroll
    for (int o = 32; o > 0; o >>= 1) v += __shfl_down(v, o, 64);
    return v;
}

// Round-5 = round-0 (best measured: 54.4us, VALU 52%, VGPR 52, no spill)
// plus ONE change: register prefetch of the next chunk's 4 float4s in both
// streaming loops. Rationale: with #pragma unroll 1 each iteration opened
// with a vmcnt(0) load-use stall (~200-500cy L2 latency) at only 4 waves/
// SIMD; the prefetch moves that wait behind the body's VALU work.
// Prefetch was proven spill-free in this config (round 1: VGPR 52->56,
// WRITE_SIZE 16KB) -- round-1's 5x regression was the flat atomics, reverted.
// Tripwires for this round: WRITE_SIZE ~16KB, FETCH ~2.2MB, VGPR <= ~70.
// Config rules learned: launch_bounds min-waves=8 => compiler clamps to 32
// VGPRs (spills any R=2 body); NT=1024 ditto; keep bounds(512,4).
__global__ __launch_bounds__(NT, 4) void akl_rows(
    const float* __restrict__ h1, const float* __restrict__ e1,
    const float* __restrict__ h3, const float* __restrict__ e3,
    float* __restrict__ out)
{
    const int tid  = threadIdx.x;
    const int lane = tid & 63, wid = tid >> 6;   // 8 waves
    const int row0 = blockIdx.x * R;

    __shared__ float pool[16384];  // 64 KB
    // P1: region q = r*4 + class (q=0..7), base q*2048, slot = bin*512 + tid
    // P2: fine e2 row r: base r*4096; fine gap row r: base (2+r)*4096
    __shared__ float red[48];
    __shared__ float shCS[R*KC];
    __shared__ float shFP[R*KF], shFG[R*KF];
    __shared__ float shA[R][7];    // c, thr, fkl, rkl, icwF, c0Fs, Spre

    // Per-row coefficients, log2 domain
    float a1L[R], b1L[R], a2L[R], b2L[R], mh1L[R], mh2L[R], icwC[R], c0C[R];
    #pragma unroll
    for (int r = 0; r < R; r++) {
        a1L[r] = h1[2*(row0+r)] * L2E; b1L[r] = h1[2*(row0+r)+1] * L2E;
        a2L[r] = h3[2*(row0+r)] * L2E; b2L[r] = h3[2*(row0+r)+1] * L2E;
        mh1L[r] = 6.0f * (fabsf(a1L[r]) + fabsf(b1L[r]));   // safe shift
        mh2L[r] = 6.0f * (fabsf(a2L[r]) + fabsf(b2L[r]));
        float sp = fmaxf(sqrtf(a2L[r]*a2L[r] + b2L[r]*b2L[r]), 1e-6f);
        icwC[r] = 1.0f / (1.35f * sp);           // 4 cells over [-0.5s, +4.9s]
        c0C[r] = 0.5f/1.35f + mh2L[r]*icwC[r];   // cb=(int)(l2s*icwC + c0C)
    }
    for (int i = tid; i < 16384; i += NT) pool[i] = 0.f;
    __syncthreads();                                                   // B0

    const float4* __restrict__ E1 = (const float4*)e1;
    const float4* __restrict__ E3 = (const float4*)e3;

    // tail: TAILN=320 is wave-aligned -> no intra-wave divergence
    const int cnt = NFULL + ((tid < TAILN) ? 1 : 0);

    // ================= Pass 1: moments + coarse 8-region partition ==========
    v2f U1v[R], S1v[R], S2v[R];
    #pragma unroll
    for (int r = 0; r < R; r++) { U1v[r] = splat2(0.f); S1v[r] = splat2(0.f); S2v[r] = splat2(0.f); }

    auto body1 = [&](float4 A0, float4 A1, float4 B0, float4 B1) {
        #pragma unroll
        for (int r = 0; r < R; r++) {
            const v2f a1v = splat2(a1L[r]), b1v = splat2(b1L[r]);
            const v2f a2v = splat2(a2L[r]), b2v = splat2(b2L[r]);
            const v2f m1v = splat2(-mh1L[r]), m2v = splat2(-mh2L[r]);
            const v2f icv = splat2(icwC[r]), c0v = splat2(c0C[r]);
            #pragma unroll
            for (int p = 0; p < 2; p++) {
                float4 A = p ? A1 : A0, B = p ? B1 : B0;
                v2f X1; X1.x = A.x; X1.y = A.z;
                v2f Y1; Y1.x = A.y; Y1.y = A.w;
                v2f X3; X3.x = B.x; X3.y = B.z;
                v2f Y3; Y3.x = B.y; Y3.y = B.w;
                v2f l1 = a1v*X1 + (b1v*Y1 + m1v);     // pk_fma
                v2f l2 = a2v*X3 + (b2v*Y3 + m2v);
                v2f e1v; e1v.x = __builtin_amdgcn_exp2f(l1.x);
                         e1v.y = __builtin_amdgcn_exp2f(l1.y);
                v2f e2v; e2v.x = __builtin_amdgcn_exp2f(l2.x);
                         e2v.y = __builtin_amdgcn_exp2f(l2.y);
                v2f dp = l2 - l1;                     // corrected post-pass
                U1v[r] += e1v;
                S1v[r] += e1v * dp;
                S2v[r] += e2v * dp;
                v2f t = l2*icv + c0v;
                float t0 = fminf(fmaxf(t.x, 0.f), 3.f);   // med3
                float t1 = fminf(fmaxf(t.y, 0.f), 3.f);
                int b0 = (int)t0, b1i = (int)t1;
                // one RMW per region per iteration: independent chains,
                // per-thread-private slots (no aliasing, bank-clean)
                float* H0 = pool + (r*4 + 2*p    )*2048;
                float* H1 = pool + (r*4 + 2*p + 1)*2048;
                H0[b0*NT + tid]  += e2v.x;
                H1[b1i*NT + tid] += e2v.y;
            }
        }
    };

    {
        float4 cA0 = E1[2*tid], cA1 = E1[2*tid+1];
        float4 cB0 = E3[2*tid], cB1 = E3[2*tid+1];
        #pragma unroll 1
        for (int it = 0; it < cnt; ++it) {
            const int jn = (it+1 < cnt) ? ((it+1)*NT + tid) : tid;  // clamped
            float4 nA0 = E1[2*jn], nA1 = E1[2*jn+1];
            float4 nB0 = E3[2*jn], nB1 = E3[2*jn+1];
            body1(cA0, cA1, cB0, cB1);
            cA0 = nA0; cA1 = nA1; cB0 = nB0; cB1 = nB1;
        }
    }

    #pragma unroll
    for (int r = 0; r < R; r++) {
        float u = wave_red_sum(U1v[r].x + U1v[r].y);
        float s1 = wave_red_sum(S1v[r].x + S1v[r].y);
        float s2 = wave_red_sum(S2v[r].x + S2v[r].y);
        if (lane == 0) {
            red[wid*6 + r*3 + 0] = u;
            red[wid*6 + r*3 + 1] = s1;
            red[wid*6 + r*3 + 2] = s2;
        }
    }
    __syncthreads();                                                   // B1

    // ---- Reduce coarse histogram: 8 groups (r x bin) x 64 lanes ----
    {
        int grp = tid >> 6, l = tid & 63;          // grp = r*KC + bin
        int r = grp >> 2, b = grp & 3;
        float s = 0.f;
        #pragma unroll
        for (int c = 0; c < 4; c++) {
            const float* H = pool + (r*4 + c)*2048 + b*512;
            #pragma unroll
            for (int t = 0; t < 8; t++) s += H[l + t*64];
        }
        s = wave_red_sum(s);
        if (l == 0) shCS[grp] = s;
    }
    __syncthreads();                                                   // B2

    // ---- Row params + coarse crossing cell (one thread per row) ----
    if (tid < R) {
        const int r = tid;
        float U1s = 0, S1s = 0, S2s = 0;
        for (int w = 0; w < 8; w++) {
            U1s += red[w*6 + r*3 + 0];
            S1s += red[w*6 + r*3 + 1];
            S2s += red[w*6 + r*3 + 2];
        }
        float U2s = 0.f;
        #pragma unroll
        for (int i = 0; i < KC; i++) U2s += shCS[r*KC + i];
        float mh1r = r ? mh1L[1] : mh1L[0];
        float mh2r = r ? mh2L[1] : mh2L[0];
        float a2r = r ? a2L[1] : a2L[0];
        float b2r = r ? b2L[1] : b2L[0];
        float dmh = mh2r - mh1r;
        S1s += dmh * U1s;                        // exact shift correction
        S2s += dmh * U2s;
        float M1 = mh1r + __builtin_amdgcn_logf(U1s);
        float M2 = mh2r + __builtin_amdgcn_logf(U2s);
        float delta = M2 - M1;
        float thr = 0.5f * U2s;
        float S = 0.f; int bsel = KC-1;
        for (int i = 0; i < KC; i++) {
            float m = shCS[r*KC + i];
            if (S + m >= thr) { bsel = i; break; }
            S += m;
        }
        float sp = fmaxf(sqrtf(a2r*a2r + b2r*b2r), 1e-6f);
        float wc  = 1.35f * sp;                  // coarse cell width
        float loS_s = fmaf((float)bsel, wc, -0.5f*sp) - mh2r;  // shifted space
        float icwF = (float)KF / wc;
        shA[r][0] = U2s / U1s;                   // c (gap scale fold)
        shA[r][1] = thr;
        shA[r][2] = LN2 * (S2s/U2s - delta);     // fkl
        shA[r][3] = LN2 * (delta - S1s/U1s);     // rkl
        shA[r][4] = icwF;
        shA[r][5] = -loS_s * icwF;               // c0Fs: t=l2s*icwF+c0Fs
        shA[r][6] = S;                           // Spre (unnorm prefix below cell)
    }
    // re-zero pool for fine pass
    for (int i = tid; i < 16384; i += NT) pool[i] = 0.f;
    __syncthreads();                                                   // B3

    // ================= Pass 2: gap stats + fine partition ===================
    float cR[R], icwFl[R], c0Fl[R];
    #pragma unroll
    for (int r = 0; r < R; r++) {
        cR[r] = shA[r][0]; icwFl[r] = shA[r][4]; c0Fl[r] = shA[r][5];
    }
    v2f gtv[R], Gpv[R];
    #pragma unroll
    for (int r = 0; r < R; r++) { gtv[r] = splat2(0.f); Gpv[r] = splat2(0.f); }

    auto body2 = [&](float4 A0, float4 A1, float4 B0, float4 B1) {
        #pragma unroll
        for (int r = 0; r < R; r++) {
            const v2f a1v = splat2(a1L[r]), b1v = splat2(b1L[r]);
            const v2f a2v = splat2(a2L[r]), b2v = splat2(b2L[r]);
            const v2f m1v = splat2(-mh1L[r]), m2v = splat2(-mh2L[r]);
            const v2f cv = splat2(-cR[r]);
            const v2f icv = splat2(icwFl[r]), c0v = splat2(c0Fl[r]);
            float* HP = pool + r*4096;
            float* HG = pool + (2+r)*4096;
            #pragma unroll
            for (int p = 0; p < 2; p++) {
                float4 A = p ? A1 : A0, B = p ? B1 : B0;
                v2f X1; X1.x = A.x; X1.y = A.z;
                v2f Y1; Y1.x = A.y; Y1.y = A.w;
                v2f X3; X3.x = B.x; X3.y = B.z;
                v2f Y3; Y3.x = B.y; Y3.y = B.w;
                v2f l1 = a1v*X1 + (b1v*Y1 + m1v);
                v2f l2 = a2v*X3 + (b2v*Y3 + m2v);
                v2f e1v; e1v.x = __builtin_amdgcn_exp2f(l1.x);
                         e1v.y = __builtin_amdgcn_exp2f(l1.y);
                v2f e2v; e2v.x = __builtin_amdgcn_exp2f(l2.x);
                         e2v.y = __builtin_amdgcn_exp2f(l2.y);
                v2f d = cv*e1v + e2v;                // e2 - c*e1 (pk_fma)
                v2f gap; gap.x = fabsf(d.x); gap.y = fabsf(d.y);
                gtv[r] += gap;
                v2f t = l2*icv + c0v;
                Gpv[r].x += (t.x < 0.f) ? gap.x : 0.f;
                Gpv[r].y += (t.y < 0.f) ? gap.y : 0.f;
                if (t.x >= 0.f && t.x < (float)KF) {   // ~1% of elements
                    int fb = (int)t.x;
                    HP[fb*NT + tid] += e2v.x;
                    HG[fb*NT + tid] += gap.x;
                }
                if (t.y >= 0.f && t.y < (float)KF) {
                    int fb = (int)t.y;
                    HP[fb*NT + tid] += e2v.y;
                    HG[fb*NT + tid] += gap.y;
                }
            }
        }
    };

    {
        float4 cA0 = E1[2*tid], cA1 = E1[2*tid+1];
        float4 cB0 = E3[2*tid], cB1 = E3[2*tid+1];
        #pragma unroll 1
        for (int it = 0; it < cnt; ++it) {
            const int jn = (it+1 < cnt) ? ((it+1)*NT + tid) : tid;  // clamped
            float4 nA0 = E1[2*jn], nA1 = E1[2*jn+1];
            float4 nB0 = E3[2*jn], nB1 = E3[2*jn+1];
            body2(cA0, cA1, cB0, cB1);
            cA0 = nA0; cA1 = nA1; cB0 = nB0; cB1 = nB1;
        }
    }

    #pragma unroll
    for (int r = 0; r < R; r++) {
        float a = wave_red_sum(gtv[r].x + gtv[r].y);
        float b = wave_red_sum(Gpv[r].x + Gpv[r].y);
        if (lane == 0) { red[wid*4 + r*2 + 0] = a; red[wid*4 + r*2 + 1] = b; }
    }
    __syncthreads();                                                   // B4

    // ---- Reduce fine histograms: 32 groups x 16 lanes ----
    {
        int grp = tid >> 4, l16 = tid & 15;      // 32 groups
        int isG = grp >> 4;                      // 0: P, 1: G
        int r = (grp >> 3) & 1, b = grp & 7;
        const float* H = pool + (isG*2 + r)*4096 + b*512;
        float s = 0.f;
        #pragma unroll
        for (int t = 0; t < NT/16; t++) s += H[l16 + t*16];
        #pragma unroll
        for (int o = 8; o > 0; o >>= 1) s += __shfl_down(s, o, 64);
        if (l16 == 0) {
            if (isG) shFG[r*KF + b] = s; else shFP[r*KF + b] = s;
        }
    }
    __syncthreads();                                                   // B5

    // ---- Walk fine bins, secant-interpolate 0.5 crossing, output ----
    if (tid < R) {
        const int r = tid;
        float gts = 0, Gp = 0;
        for (int w = 0; w < 8; w++) {
            gts += red[w*4 + r*2 + 0];
            Gp  += red[w*4 + r*2 + 1];
        }
        float thr = shA[r][1], fkl = shA[r][2], rkl = shA[r][3];
        float S = shA[r][6], G = Gp;
        bool done = false;
        #pragma unroll
        for (int i = 0; i < KF; i++) {
            if (!done) {
                float p = shFP[r*KF + i], g = shFG[r*KF + i];
                float ns = S + p;
                if (ns >= thr) {
                    float f = (thr - S) / fmaxf(p, 1e-30f);
                    f = fminf(fmaxf(f, 0.f), 1.f);
                    G += f * g;
                    done = true;
                } else { S = ns; G += g; }
            }
        }
        float gl = G;                    // g_tail (unnormalized: scale cancels)
        float gh = gts - gl;             // g_head
        float akl = (gh*fkl + gl*rkl) / gts;
        unsafeAtomicAdd(out, akl * (1.0f/(float)DNUM));
    }
}

extern "C" void kernel_launch(void* const* d_in, const int* in_sizes, int n_in,
                              void* d_out, int out_size, void* d_ws, size_t ws_size,
                              hipStream_t stream) {
    const float* h1 = (const float*)d_in[0];
    const float* e1 = (const float*)d_in[1];
    const float* h3 = (const float*)d_in[2];
    const float* e3 = (const float*)d_in[3];
    hipMemsetAsync(d_out, 0, sizeof(float), stream);   // capture-safe
    akl_rows<<<GRID, NT, 0, stream>>>(h1, e1, h3, e3, (float*)d_out);
}